// Round 12
// baseline (139.672 us; speedup 1.0000x reference)
//
#include <hip/hip_runtime.h>

#define F_IN 128
#define HH1 128
#define HH2 64
#define FOUT 50
#define EB 256          // edge-pass blocks (A1/A3)
#define NBUCK_MAX 256   // max coarse buckets (n <= 64k)

typedef __attribute__((ext_vector_type(8))) short short8;
typedef __attribute__((ext_vector_type(4))) short s16x4;
typedef __attribute__((ext_vector_type(4))) float f32x4;

__device__ inline short f2bf(float f) {  // RNE fp32->bf16
    union { float f; unsigned u; } v; v.f = f;
    unsigned r = v.u + 0x7fffu + ((v.u >> 16) & 1u);
    return (short)(r >> 16);
}
__device__ inline float bf2f(short s) {
    union { float f; unsigned u; } v; v.u = ((unsigned)(unsigned short)s) << 16;
    return v.f;
}

// Per-block int64-vs-int32 self-detection: int64 node ids < 2^31 have all-zero
// high (odd) words in the first 512 int32 words. Returns 1 if int64.
__device__ inline int detect64(const unsigned* raw) {
    __shared__ int s_is64;
    if (threadIdx.x == 0) s_is64 = 1;
    __syncthreads();
    if (raw[2 * threadIdx.x + 1] != 0u) atomicAnd(&s_is64, 0);
    __syncthreads();
    return s_is64;
}

// ---- A1: coarse histogram (dst>>8) per block + fused weight transpose -------
__global__ __launch_bounds__(256) void bucket_count(
    const int* __restrict__ raw, int E, int nbuck, int* __restrict__ parthist,
    const float* __restrict__ W1, const float* __restrict__ W2,
    const float* __restrict__ Wh, short* __restrict__ W1t,
    short* __restrict__ W2t, short* __restrict__ Wht) {
    __shared__ int hist[NBUCK_MAX];
    const int tid = threadIdx.x;
    int is64 = detect64((const unsigned*)raw);
    for (int k = tid; k < nbuck; k += 256) hist[k] = 0;
    __syncthreads();
    const int CH = (E + EB - 1) / EB;
    const int e0 = blockIdx.x * CH, e1 = min(E, e0 + CH);
    for (int e = e0 + tid; e < e1; e += 256) {
        int d = is64 ? raw[2 * (long)E + 2 * e] : raw[E + e];
        atomicAdd(&hist[d >> 8], 1);
    }
    __syncthreads();
    for (int k = tid; k < nbuck; k += 256) parthist[blockIdx.x * nbuck + k] = hist[k];
    // fused weight transpose (independent work)
    const int T1 = HH1 * F_IN, T2 = HH2 * HH1, T3 = 64 * HH2;
    int idx = blockIdx.x * 256 + tid;
    if (idx < T1) {
        int c = idx / F_IN, k = idx - c * F_IN;
        W1t[idx] = f2bf(W1[(long)k * HH1 + c]);
    } else if (idx < T1 + T2) {
        int i = idx - T1;
        int c = i / HH1, k = i - c * HH1;
        W2t[i] = f2bf(W2[(long)k * HH2 + c]);
    } else if (idx < T1 + T2 + T3) {
        int i = idx - T1 - T2;
        int c = i / HH2, k = i - c * HH2;
        Wht[i] = f2bf((c < FOUT) ? Wh[(long)k * FOUT + c] : 0.f);
    }
}

// ---- A2: PARALLEL column scan + (last block) bucket-base scan ---------------
__global__ __launch_bounds__(256) void scan_cols(
    int* __restrict__ parthist, int* __restrict__ totals, int* __restrict__ bbase,
    unsigned* __restrict__ done, int nbuck, int E) {
    const int k = blockIdx.x;   // 0..255
    const int t = threadIdx.x;
    __shared__ int sh[256];
    int v = 0;
    if (k < nbuck) v = parthist[t * nbuck + k];
    sh[t] = v;
    __syncthreads();
    for (int off = 1; off < 256; off <<= 1) {
        int tv = (t >= off) ? sh[t - off] : 0;
        __syncthreads();
        sh[t] += tv;
        __syncthreads();
    }
    if (k < nbuck) parthist[t * nbuck + k] = sh[t] - v;  // exclusive col-prefix
    if (t == 255) totals[k] = (k < nbuck) ? sh[255] : 0;
    __threadfence();
    __syncthreads();
    __shared__ unsigned s_old;
    if (t == 0) s_old = atomicAdd(done, 1u);
    __syncthreads();
    if (s_old % 256u != 255u) return;
    __threadfence();  // acquire: see all blocks' totals/parthist writes
    int tv2 = totals[t];
    sh[t] = tv2;
    __syncthreads();
    for (int off = 1; off < 256; off <<= 1) {
        int tt = (t >= off) ? sh[t - off] : 0;
        __syncthreads();
        sh[t] += tt;
        __syncthreads();
    }
    if (t < nbuck) bbase[t] = sh[t] - tv2;  // exclusive
    if (t == 0) bbase[nbuck] = E;
}

// ---- A3 + layer-1 GEMM merged in one dispatch -------------------------------
__global__ __launch_bounds__(256) void scatter_gemm1(
    const int* __restrict__ raw, int E, int nbuck,
    const int* __restrict__ parthist, const int* __restrict__ bbase,
    int2* __restrict__ tmp,
    const float* __restrict__ x, const short* __restrict__ W1t,
    short* __restrict__ h1, int n) {
    const int tid = threadIdx.x;
    if (blockIdx.x < EB) {
        __shared__ int cur[NBUCK_MAX];
        int is64 = detect64((const unsigned*)raw);
        for (int k = tid; k < nbuck; k += 256)
            cur[k] = bbase[k] + parthist[blockIdx.x * nbuck + k];
        __syncthreads();
        const int CH = (E + EB - 1) / EB;
        const int e0 = blockIdx.x * CH, e1 = min(E, e0 + CH);
        for (int e = e0 + tid; e < e1; e += 256) {
            int s, d;
            if (is64) {
                s = raw[2 * e];
                d = raw[2 * (long)E + 2 * e];
            } else {
                s = raw[e];
                d = raw[E + e];
            }
            int pos = atomicAdd(&cur[d >> 8], 1);
            tmp[pos] = make_int2(s, d);
        }
        return;
    }
    // ---- GEMM1 part ----
    const int bid = blockIdx.x - EB;
    const int wave = tid >> 6;
    const int lane = tid & 63;
    const int l15 = lane & 15;
    const int kg = lane >> 4;
    const int rowbase = bid * 64 + wave * 16;
    const int arow = rowbase + l15;
    constexpr int KS = F_IN / 32;

    short8 af[KS];
    if (arow < n) {
        const float* xr = x + (long)arow * F_IN + kg * 8;
#pragma unroll
        for (int ks = 0; ks < KS; ++ks) {
            float4 f0 = *(const float4*)(xr + ks * 32);
            float4 f1 = *(const float4*)(xr + ks * 32 + 4);
            short8 a;
            a[0] = f2bf(f0.x); a[1] = f2bf(f0.y); a[2] = f2bf(f0.z); a[3] = f2bf(f0.w);
            a[4] = f2bf(f1.x); a[5] = f2bf(f1.y); a[6] = f2bf(f1.z); a[7] = f2bf(f1.w);
            af[ks] = a;
        }
    } else {
#pragma unroll
        for (int ks = 0; ks < KS; ++ks) af[ks] = (short8)0;
    }
    const int crowb = rowbase + kg * 4;
#pragma unroll
    for (int ct = 0; ct < HH1 / 16; ++ct) {
        const int col = ct * 16 + l15;
        const short* wr = W1t + (long)col * F_IN + kg * 8;
        f32x4 acc = {0.f, 0.f, 0.f, 0.f};
#pragma unroll
        for (int ks = 0; ks < KS; ++ks) {
            short8 bfr = *(const short8*)(wr + ks * 32);
            acc = __builtin_amdgcn_mfma_f32_16x16x32_bf16(af[ks], bfr, acc, 0, 0, 0);
        }
#pragma unroll
        for (int j = 0; j < 4; ++j) {
            int r = crowb + j;
            if (r < n) h1[(long)r * HH1 + col] = f2bf(acc[j]);
        }
    }
}

// ---- B: per-bucket fine sort -> rowptr, dinv, csr_src -----------------------
__global__ __launch_bounds__(256) void bucket_finalize(
    const int2* __restrict__ tmp, const int* __restrict__ bbase,
    int* __restrict__ rowptr, float* __restrict__ dinv,
    int* __restrict__ csr_src, int n, int nbuck) {
    __shared__ int deg[256];
    __shared__ int cur[256];
    __shared__ int sh[256];
    const int k = blockIdx.x;
    const int tid = threadIdx.x;
    const int b0 = bbase[k], b1 = bbase[k + 1];
    deg[tid] = 0;
    __syncthreads();
    for (int e = b0 + tid; e < b1; e += 256) atomicAdd(&deg[tmp[e].y & 255], 1);
    __syncthreads();
    int v = deg[tid];
    sh[tid] = v;
    __syncthreads();
    for (int off = 1; off < 256; off <<= 1) {
        int t = (tid >= off) ? sh[tid - off] : 0;
        __syncthreads();
        sh[tid] += t;
        __syncthreads();
    }
    int excl = sh[tid] - v;
    cur[tid] = excl;
    int node = (k << 8) + tid;
    if (node < n) {
        rowptr[node] = b0 + excl;
        dinv[node] = rsqrtf((float)v + 1.0f);  // +1 self-loop
    }
    if (k == 0 && tid == 0) rowptr[n] = bbase[nbuck];
    __syncthreads();
    for (int e = b0 + tid; e < b1; e += 256) {
        int2 sd = tmp[e];
        int p = atomicAdd(&cur[sd.y & 255], 1);
        csr_src[b0 + p] = sd.x;
    }
}

// ---- pre-scale h1 in place: h1[i] *= dinv[row(i)] ---------------------------
__global__ __launch_bounds__(256) void scale_h1(short* __restrict__ h1,
                                                const float* __restrict__ dinv,
                                                int n) {
    int idx = blockIdx.x * 256 + threadIdx.x;   // one short8 (=8 bf16) per thread
    int total = n * (HH1 / 8);
    if (idx >= total) return;
    int node = idx >> 4;                        // HH1/8 = 16 short8 per row
    float d = dinv[node];
    short8 v = ((const short8*)h1)[idx];
    short8 o;
#pragma unroll
    for (int j = 0; j < 8; ++j) o[j] = f2bf(d * bf2f(v[j]));
    ((short8*)h1)[idx] = o;
}

// ---- gather helpers: PURE SUM (features pre-scaled by dinv[src]) ------------
template <int FPL>
__device__ inline void gadd1(const short* p0, float* acc) {
    if constexpr (FPL == 8) {
        short8 v0 = *(const short8*)p0;
#pragma unroll
        for (int j = 0; j < 8; ++j) acc[j] += bf2f(v0[j]);
    } else {
        s16x4 v0 = *(const s16x4*)p0;
#pragma unroll
        for (int j = 0; j < 4; ++j) acc[j] += bf2f(v0[j]);
    }
}

// ---- fused aggregate + GEMM (pre-scaled features) ---------------------------
// Per block: 16 nodes. Phase 1: 16 lanes/node pure-sum gather (4-wide ILP):
//   acc = h'[node] + sum_e h'[src]           (h' = dinv*h)
//   tile = relu(bias_pre + dinv[node]*acc)  -> bf16 LDS [16][FW+8]
// Phase 2: 4 waves, wave w computes cols w*16..+15 of tile @ Wt^T.
//   !OUT_F32: writes Y = bf16(dinv[row] * (tile@Wt))  (pre-scaled for next agg)
//   OUT_F32:  writes fp32 out + bias_post (head)
template <int FW, bool OUT_F32>
__global__ __launch_bounds__(256) void agg_mm(
    const short* __restrict__ h, const int* __restrict__ rowptr,
    const int* __restrict__ csr_src, const float* __restrict__ dinv,
    const float* __restrict__ bias_pre, const short* __restrict__ Wt,
    const float* __restrict__ bias_post, void* __restrict__ Yv, int n,
    int ncreal) {
    constexpr int FPL = FW / 16;   // bf16 feats per lane (8 or 4)
    constexpr int LDW = FW + 8;    // padded row
    constexpr int KS = FW / 32;
    __shared__ short tile[16][LDW];
    const int tid = threadIdx.x;
    const int grp = tid >> 4;
    const int l16 = tid & 15;
    const int node = blockIdx.x * 16 + grp;

    float acc[FPL];
#pragma unroll
    for (int j = 0; j < FPL; ++j) acc[j] = 0.f;
    float di = 0.f;

    if (node < n) {
        di = dinv[node];
        gadd1<FPL>(h + (long)node * FW + l16 * FPL, acc);  // self-loop term h'[node]
        int e = rowptr[node];
        const int end = rowptr[node + 1];
        for (; e + 3 < end; e += 4) {  // 4 independent gathers in flight
            int s0 = csr_src[e];
            int s1 = csr_src[e + 1];
            int s2 = csr_src[e + 2];
            int s3 = csr_src[e + 3];
            const short* p0 = h + (long)s0 * FW + l16 * FPL;
            const short* p1 = h + (long)s1 * FW + l16 * FPL;
            const short* p2 = h + (long)s2 * FW + l16 * FPL;
            const short* p3 = h + (long)s3 * FW + l16 * FPL;
            if constexpr (FPL == 8) {
                short8 v0 = *(const short8*)p0;
                short8 v1 = *(const short8*)p1;
                short8 v2 = *(const short8*)p2;
                short8 v3 = *(const short8*)p3;
#pragma unroll
                for (int j = 0; j < 8; ++j) acc[j] += bf2f(v0[j]);
#pragma unroll
                for (int j = 0; j < 8; ++j) acc[j] += bf2f(v1[j]);
#pragma unroll
                for (int j = 0; j < 8; ++j) acc[j] += bf2f(v2[j]);
#pragma unroll
                for (int j = 0; j < 8; ++j) acc[j] += bf2f(v3[j]);
            } else {
                s16x4 v0 = *(const s16x4*)p0;
                s16x4 v1 = *(const s16x4*)p1;
                s16x4 v2 = *(const s16x4*)p2;
                s16x4 v3 = *(const s16x4*)p3;
#pragma unroll
                for (int j = 0; j < 4; ++j) acc[j] += bf2f(v0[j]);
#pragma unroll
                for (int j = 0; j < 4; ++j) acc[j] += bf2f(v1[j]);
#pragma unroll
                for (int j = 0; j < 4; ++j) acc[j] += bf2f(v2[j]);
#pragma unroll
                for (int j = 0; j < 4; ++j) acc[j] += bf2f(v3[j]);
            }
        }
        for (; e < end; ++e)
            gadd1<FPL>(h + (long)csr_src[e] * FW + l16 * FPL, acc);
    }
    // tile = relu(bias + di*acc) -> bf16 (OOB rows: acc=0, di=0 -> relu(bias)?
    // No: OOB rows must be zero for MFMA padding; guard with node<n.)
    if constexpr (FPL == 8) {
        short8 o;
#pragma unroll
        for (int j = 0; j < 8; ++j) {
            float t = (node < n) ? fmaf(di, acc[j], bias_pre[l16 * 8 + j]) : 0.f;
            o[j] = f2bf(fmaxf(t, 0.f));
        }
        *(short8*)&tile[grp][l16 * 8] = o;
    } else {
        s16x4 o;
#pragma unroll
        for (int j = 0; j < 4; ++j) {
            float t = (node < n) ? fmaf(di, acc[j], bias_pre[l16 * 4 + j]) : 0.f;
            o[j] = f2bf(fmaxf(t, 0.f));
        }
        *(s16x4*)&tile[grp][l16 * 4] = o;
    }
    __syncthreads();

    // MFMA: tile[16][FW] @ Wt^T -> [16][64]
    const int wave = tid >> 6;
    const int lane = tid & 63;
    const int l15 = lane & 15;
    const int kg = lane >> 4;
    const int col = wave * 16 + l15;
    short8 af[KS];
#pragma unroll
    for (int ks = 0; ks < KS; ++ks)
        af[ks] = *(const short8*)&tile[l15][kg * 8 + ks * 32];
    f32x4 c2 = {0.f, 0.f, 0.f, 0.f};
    const short* wr = Wt + (long)col * FW + kg * 8;
#pragma unroll
    for (int ks = 0; ks < KS; ++ks) {
        short8 bfr = *(const short8*)(wr + ks * 32);
        c2 = __builtin_amdgcn_mfma_f32_16x16x32_bf16(af[ks], bfr, c2, 0, 0, 0);
    }
    const int rb = blockIdx.x * 16 + kg * 4;
    if (OUT_F32) {
        float* Y = (float*)Yv;
#pragma unroll
        for (int j = 0; j < 4; ++j) {
            int g = rb + j;
            if (g < n && col < ncreal)
                Y[(long)g * ncreal + col] = c2[j] + bias_post[col];
        }
    } else {
        short* Y = (short*)Yv;
#pragma unroll
        for (int j = 0; j < 4; ++j) {
            int g = rb + j;
            if (g < n) Y[(long)g * 64 + col] = f2bf(dinv[g] * c2[j]);  // pre-scaled
        }
    }
}

// ---- launch -----------------------------------------------------------------
static inline size_t al256(size_t x) { return (x + 255) & ~(size_t)255; }

extern "C" void kernel_launch(void* const* d_in, const int* in_sizes, int n_in,
                              void* d_out, int out_size, void* d_ws, size_t ws_size,
                              hipStream_t stream) {
    const float* x    = (const float*)d_in[0];
    const int*   eraw = (const int*)d_in[1];
    const float* W1   = (const float*)d_in[2];
    const float* b1   = (const float*)d_in[3];
    const float* W2   = (const float*)d_in[4];
    const float* b2   = (const float*)d_in[5];
    const float* Wh   = (const float*)d_in[6];
    const float* bh   = (const float*)d_in[7];
    float* out = (float*)d_out;
    const int n = in_sizes[0] / F_IN;
    const int E = in_sizes[1] / 2;
    const int nbuck = (n + 255) >> 8;  // 196 for n=50k

    // ---- workspace layout ----
    char* p = (char*)d_ws;
    unsigned* done  = (unsigned*)p; p += 256;     // modulo-trick counter (no init needed)
    float* dinv     = (float*)p; p += al256((size_t)n * 4);
    int*   rowptr   = (int*)p;   p += al256((size_t)(n + 1) * 4);
    int*   parthist = (int*)p;   p += al256((size_t)EB * nbuck * 4);
    int*   totals   = (int*)p;   p += al256((size_t)NBUCK_MAX * 4);
    int*   bbase    = (int*)p;   p += al256((size_t)(nbuck + 1) * 4);
    int*   csr_src  = (int*)p;   p += al256((size_t)E * 4);
    short* W1t      = (short*)p; p += al256((size_t)HH1 * F_IN * 2);
    short* W2t      = (short*)p; p += al256((size_t)HH2 * HH1 * 2);
    short* Whtp     = (short*)p; p += al256((size_t)64 * HH2 * 2);
    int2*  tmp      = (int2*)p;  p += al256((size_t)E * 8);         // 5 MB
    short* h1       = (short*)p; p += al256((size_t)n * HH1 * 2);   // 12.8 MB
    short* h2       = (short*)p;                                    // 6.4 MB

    dim3 blk(256);
    // CSR build: histogram -> parallel column scan -> scatter (overlapped w/ GEMM1)
    bucket_count<<<EB, blk, 0, stream>>>(eraw, E, nbuck, parthist,
                                         W1, W2, Wh, W1t, W2t, Whtp);
    scan_cols<<<NBUCK_MAX, blk, 0, stream>>>(parthist, totals, bbase, done, nbuck, E);
    scatter_gemm1<<<EB + (n + 63) / 64, blk, 0, stream>>>(
        eraw, E, nbuck, parthist, bbase, tmp, x, W1t, h1, n);
    bucket_finalize<<<nbuck, blk, 0, stream>>>(tmp, bbase, rowptr, dinv, csr_src, n, nbuck);
    // pre-scale h1 by dinv (enables coefficient-free gathers)
    scale_h1<<<(n * (HH1 / 8) + 255) / 256, blk, 0, stream>>>(h1, dinv, n);

    // fused: agg(h1')+b1+relu -> @W2 -> h2' (pre-scaled in epilogue)
    agg_mm<HH1, false><<<(n + 15) / 16, blk, 0, stream>>>(
        h1, rowptr, csr_src, dinv, b1, W2t, nullptr, h2, n, HH2);
    // fused: agg(h2')+b2+relu -> @Wh + bh -> out (fp32, 50 cols)
    agg_mm<HH2, true><<<(n + 15) / 16, blk, 0, stream>>>(
        h2, rowptr, csr_src, dinv, b2, Whtp, bh, out, n, FOUT);
}

// Round 13
// 135.652 us; speedup vs baseline: 1.0296x; 1.0296x over previous
//
#include <hip/hip_runtime.h>

#define F_IN 128
#define HH1 128
#define HH2 64
#define FOUT 50
#define EB 256          // edge-pass blocks (A1/A3)
#define NBUCK_MAX 256   // max coarse buckets (n <= 64k)

typedef __attribute__((ext_vector_type(8))) short short8;
typedef __attribute__((ext_vector_type(4))) short s16x4;
typedef __attribute__((ext_vector_type(4))) float f32x4;

__device__ inline short f2bf(float f) {  // RNE fp32->bf16
    union { float f; unsigned u; } v; v.f = f;
    unsigned r = v.u + 0x7fffu + ((v.u >> 16) & 1u);
    return (short)(r >> 16);
}
__device__ inline float bf2f(short s) {
    union { float f; unsigned u; } v; v.u = ((unsigned)(unsigned short)s) << 16;
    return v.f;
}

// Per-block int64-vs-int32 self-detection: int64 node ids < 2^31 have all-zero
// high (odd) words in the first 512 int32 words. Returns 1 if int64.
__device__ inline int detect64(const unsigned* raw) {
    __shared__ int s_is64;
    if (threadIdx.x == 0) s_is64 = 1;
    __syncthreads();
    if (raw[2 * threadIdx.x + 1] != 0u) atomicAnd(&s_is64, 0);
    __syncthreads();
    return s_is64;
}

// ---- A1: coarse histogram (dst>>8) per block + fused weight transpose -------
__global__ __launch_bounds__(256) void bucket_count(
    const int* __restrict__ raw, int E, int nbuck, int* __restrict__ parthist,
    const float* __restrict__ W1, const float* __restrict__ W2,
    const float* __restrict__ Wh, short* __restrict__ W1t,
    short* __restrict__ W2t, short* __restrict__ Wht) {
    __shared__ int hist[NBUCK_MAX];
    const int tid = threadIdx.x;
    int is64 = detect64((const unsigned*)raw);
    for (int k = tid; k < nbuck; k += 256) hist[k] = 0;
    __syncthreads();
    const int CH = (E + EB - 1) / EB;
    const int e0 = blockIdx.x * CH, e1 = min(E, e0 + CH);
    for (int e = e0 + tid; e < e1; e += 256) {
        int d = is64 ? raw[2 * (long)E + 2 * e] : raw[E + e];
        atomicAdd(&hist[d >> 8], 1);
    }
    __syncthreads();
    for (int k = tid; k < nbuck; k += 256) parthist[blockIdx.x * nbuck + k] = hist[k];
    // fused weight transpose (independent work)
    const int T1 = HH1 * F_IN, T2 = HH2 * HH1, T3 = 64 * HH2;
    int idx = blockIdx.x * 256 + tid;
    if (idx < T1) {
        int c = idx / F_IN, k = idx - c * F_IN;
        W1t[idx] = f2bf(W1[(long)k * HH1 + c]);
    } else if (idx < T1 + T2) {
        int i = idx - T1;
        int c = i / HH1, k = i - c * HH1;
        W2t[i] = f2bf(W2[(long)k * HH2 + c]);
    } else if (idx < T1 + T2 + T3) {
        int i = idx - T1 - T2;
        int c = i / HH2, k = i - c * HH2;
        Wht[i] = f2bf((c < FOUT) ? Wh[(long)k * FOUT + c] : 0.f);
    }
}

// ---- A2: PARALLEL column scan + (last block) bucket-base scan ---------------
__global__ __launch_bounds__(256) void scan_cols(
    int* __restrict__ parthist, int* __restrict__ totals, int* __restrict__ bbase,
    unsigned* __restrict__ done, int nbuck, int E) {
    const int k = blockIdx.x;   // 0..255
    const int t = threadIdx.x;
    __shared__ int sh[256];
    int v = 0;
    if (k < nbuck) v = parthist[t * nbuck + k];
    sh[t] = v;
    __syncthreads();
    for (int off = 1; off < 256; off <<= 1) {
        int tv = (t >= off) ? sh[t - off] : 0;
        __syncthreads();
        sh[t] += tv;
        __syncthreads();
    }
    if (k < nbuck) parthist[t * nbuck + k] = sh[t] - v;  // exclusive col-prefix
    if (t == 255) totals[k] = (k < nbuck) ? sh[255] : 0;
    __threadfence();
    __syncthreads();
    __shared__ unsigned s_old;
    if (t == 0) s_old = atomicAdd(done, 1u);
    __syncthreads();
    if (s_old % 256u != 255u) return;
    __threadfence();  // acquire: see all blocks' totals/parthist writes
    int tv2 = totals[t];
    sh[t] = tv2;
    __syncthreads();
    for (int off = 1; off < 256; off <<= 1) {
        int tt = (t >= off) ? sh[t - off] : 0;
        __syncthreads();
        sh[t] += tt;
        __syncthreads();
    }
    if (t < nbuck) bbase[t] = sh[t] - tv2;  // exclusive
    if (t == 0) bbase[nbuck] = E;
}

// ---- A3 + layer-1 GEMM merged in one dispatch -------------------------------
__global__ __launch_bounds__(256) void scatter_gemm1(
    const int* __restrict__ raw, int E, int nbuck,
    const int* __restrict__ parthist, const int* __restrict__ bbase,
    int2* __restrict__ tmp,
    const float* __restrict__ x, const short* __restrict__ W1t,
    short* __restrict__ h1, int n) {
    const int tid = threadIdx.x;
    if (blockIdx.x < EB) {
        __shared__ int cur[NBUCK_MAX];
        int is64 = detect64((const unsigned*)raw);
        for (int k = tid; k < nbuck; k += 256)
            cur[k] = bbase[k] + parthist[blockIdx.x * nbuck + k];
        __syncthreads();
        const int CH = (E + EB - 1) / EB;
        const int e0 = blockIdx.x * CH, e1 = min(E, e0 + CH);
        for (int e = e0 + tid; e < e1; e += 256) {
            int s, d;
            if (is64) {
                s = raw[2 * e];
                d = raw[2 * (long)E + 2 * e];
            } else {
                s = raw[e];
                d = raw[E + e];
            }
            int pos = atomicAdd(&cur[d >> 8], 1);
            tmp[pos] = make_int2(s, d);
        }
        return;
    }
    // ---- GEMM1 part ----
    const int bid = blockIdx.x - EB;
    const int wave = tid >> 6;
    const int lane = tid & 63;
    const int l15 = lane & 15;
    const int kg = lane >> 4;
    const int rowbase = bid * 64 + wave * 16;
    const int arow = rowbase + l15;
    constexpr int KS = F_IN / 32;

    short8 af[KS];
    if (arow < n) {
        const float* xr = x + (long)arow * F_IN + kg * 8;
#pragma unroll
        for (int ks = 0; ks < KS; ++ks) {
            float4 f0 = *(const float4*)(xr + ks * 32);
            float4 f1 = *(const float4*)(xr + ks * 32 + 4);
            short8 a;
            a[0] = f2bf(f0.x); a[1] = f2bf(f0.y); a[2] = f2bf(f0.z); a[3] = f2bf(f0.w);
            a[4] = f2bf(f1.x); a[5] = f2bf(f1.y); a[6] = f2bf(f1.z); a[7] = f2bf(f1.w);
            af[ks] = a;
        }
    } else {
#pragma unroll
        for (int ks = 0; ks < KS; ++ks) af[ks] = (short8)0;
    }
    const int crowb = rowbase + kg * 4;
#pragma unroll
    for (int ct = 0; ct < HH1 / 16; ++ct) {
        const int col = ct * 16 + l15;
        const short* wr = W1t + (long)col * F_IN + kg * 8;
        f32x4 acc = {0.f, 0.f, 0.f, 0.f};
#pragma unroll
        for (int ks = 0; ks < KS; ++ks) {
            short8 bfr = *(const short8*)(wr + ks * 32);
            acc = __builtin_amdgcn_mfma_f32_16x16x32_bf16(af[ks], bfr, acc, 0, 0, 0);
        }
#pragma unroll
        for (int j = 0; j < 4; ++j) {
            int r = crowb + j;
            if (r < n) h1[(long)r * HH1 + col] = f2bf(acc[j]);
        }
    }
}

// ---- B: per-bucket fine sort -> rowptr, dinv, csr_src -----------------------
__global__ __launch_bounds__(256) void bucket_finalize(
    const int2* __restrict__ tmp, const int* __restrict__ bbase,
    int* __restrict__ rowptr, float* __restrict__ dinv,
    int* __restrict__ csr_src, int n, int nbuck) {
    __shared__ int deg[256];
    __shared__ int cur[256];
    __shared__ int sh[256];
    const int k = blockIdx.x;
    const int tid = threadIdx.x;
    const int b0 = bbase[k], b1 = bbase[k + 1];
    deg[tid] = 0;
    __syncthreads();
    for (int e = b0 + tid; e < b1; e += 256) atomicAdd(&deg[tmp[e].y & 255], 1);
    __syncthreads();
    int v = deg[tid];
    sh[tid] = v;
    __syncthreads();
    for (int off = 1; off < 256; off <<= 1) {
        int t = (tid >= off) ? sh[tid - off] : 0;
        __syncthreads();
        sh[tid] += t;
        __syncthreads();
    }
    int excl = sh[tid] - v;
    cur[tid] = excl;
    int node = (k << 8) + tid;
    if (node < n) {
        rowptr[node] = b0 + excl;
        dinv[node] = rsqrtf((float)v + 1.0f);  // +1 self-loop
    }
    if (k == 0 && tid == 0) rowptr[n] = bbase[nbuck];
    __syncthreads();
    for (int e = b0 + tid; e < b1; e += 256) {
        int2 sd = tmp[e];
        int p = atomicAdd(&cur[sd.y & 255], 1);
        csr_src[b0 + p] = sd.x;
    }
}

// ---- gather helpers (coef form; fma order = ascending edge index) -----------
template <int FW>
__device__ inline void gather1(const short* __restrict__ h,
                               const float* __restrict__ dinv, float di,
                               int s0, int l16, float* acc) {
    constexpr int FPL = FW / 16;
    const short* p0 = h + (long)s0 * FW + l16 * FPL;
    float c0 = dinv[s0] * di;
    if constexpr (FPL == 8) {
        short8 v0 = *(const short8*)p0;
#pragma unroll
        for (int j = 0; j < 8; ++j) acc[j] = fmaf(c0, bf2f(v0[j]), acc[j]);
    } else {
        s16x4 v0 = *(const s16x4*)p0;
#pragma unroll
        for (int j = 0; j < 4; ++j) acc[j] = fmaf(c0, bf2f(v0[j]), acc[j]);
    }
}
template <int FW>
__device__ inline void gather4(const short* __restrict__ h,
                               const float* __restrict__ dinv, float di,
                               int4 s4, int l16, float* acc) {
    constexpr int FPL = FW / 16;
    const short* p0 = h + (long)s4.x * FW + l16 * FPL;
    const short* p1 = h + (long)s4.y * FW + l16 * FPL;
    const short* p2 = h + (long)s4.z * FW + l16 * FPL;
    const short* p3 = h + (long)s4.w * FW + l16 * FPL;
    float c0 = dinv[s4.x] * di;
    float c1 = dinv[s4.y] * di;
    float c2 = dinv[s4.z] * di;
    float c3 = dinv[s4.w] * di;
    if constexpr (FPL == 8) {
        short8 v0 = *(const short8*)p0;
        short8 v1 = *(const short8*)p1;
        short8 v2 = *(const short8*)p2;
        short8 v3 = *(const short8*)p3;
#pragma unroll
        for (int j = 0; j < 8; ++j) acc[j] = fmaf(c0, bf2f(v0[j]), acc[j]);
#pragma unroll
        for (int j = 0; j < 8; ++j) acc[j] = fmaf(c1, bf2f(v1[j]), acc[j]);
#pragma unroll
        for (int j = 0; j < 8; ++j) acc[j] = fmaf(c2, bf2f(v2[j]), acc[j]);
#pragma unroll
        for (int j = 0; j < 8; ++j) acc[j] = fmaf(c3, bf2f(v3[j]), acc[j]);
    } else {
        s16x4 v0 = *(const s16x4*)p0;
        s16x4 v1 = *(const s16x4*)p1;
        s16x4 v2 = *(const s16x4*)p2;
        s16x4 v3 = *(const s16x4*)p3;
#pragma unroll
        for (int j = 0; j < 4; ++j) acc[j] = fmaf(c0, bf2f(v0[j]), acc[j]);
#pragma unroll
        for (int j = 0; j < 4; ++j) acc[j] = fmaf(c1, bf2f(v1[j]), acc[j]);
#pragma unroll
        for (int j = 0; j < 4; ++j) acc[j] = fmaf(c2, bf2f(v2[j]), acc[j]);
#pragma unroll
        for (int j = 0; j < 4; ++j) acc[j] = fmaf(c3, bf2f(v3[j]), acc[j]);
    }
}
// 8 independent gathers in flight; fma order still e..e+7 ascending.
template <int FW>
__device__ inline void gather8(const short* __restrict__ h,
                               const float* __restrict__ dinv, float di,
                               int4 sa, int4 sb, int l16, float* acc) {
    constexpr int FPL = FW / 16;
    const short* p0 = h + (long)sa.x * FW + l16 * FPL;
    const short* p1 = h + (long)sa.y * FW + l16 * FPL;
    const short* p2 = h + (long)sa.z * FW + l16 * FPL;
    const short* p3 = h + (long)sa.w * FW + l16 * FPL;
    const short* p4 = h + (long)sb.x * FW + l16 * FPL;
    const short* p5 = h + (long)sb.y * FW + l16 * FPL;
    const short* p6 = h + (long)sb.z * FW + l16 * FPL;
    const short* p7 = h + (long)sb.w * FW + l16 * FPL;
    float c0 = dinv[sa.x] * di, c1 = dinv[sa.y] * di;
    float c2 = dinv[sa.z] * di, c3 = dinv[sa.w] * di;
    float c4 = dinv[sb.x] * di, c5 = dinv[sb.y] * di;
    float c6 = dinv[sb.z] * di, c7 = dinv[sb.w] * di;
    if constexpr (FPL == 8) {
        short8 v0 = *(const short8*)p0;
        short8 v1 = *(const short8*)p1;
        short8 v2 = *(const short8*)p2;
        short8 v3 = *(const short8*)p3;
        short8 v4 = *(const short8*)p4;
        short8 v5 = *(const short8*)p5;
        short8 v6 = *(const short8*)p6;
        short8 v7 = *(const short8*)p7;
#pragma unroll
        for (int j = 0; j < 8; ++j) acc[j] = fmaf(c0, bf2f(v0[j]), acc[j]);
#pragma unroll
        for (int j = 0; j < 8; ++j) acc[j] = fmaf(c1, bf2f(v1[j]), acc[j]);
#pragma unroll
        for (int j = 0; j < 8; ++j) acc[j] = fmaf(c2, bf2f(v2[j]), acc[j]);
#pragma unroll
        for (int j = 0; j < 8; ++j) acc[j] = fmaf(c3, bf2f(v3[j]), acc[j]);
#pragma unroll
        for (int j = 0; j < 8; ++j) acc[j] = fmaf(c4, bf2f(v4[j]), acc[j]);
#pragma unroll
        for (int j = 0; j < 8; ++j) acc[j] = fmaf(c5, bf2f(v5[j]), acc[j]);
#pragma unroll
        for (int j = 0; j < 8; ++j) acc[j] = fmaf(c6, bf2f(v6[j]), acc[j]);
#pragma unroll
        for (int j = 0; j < 8; ++j) acc[j] = fmaf(c7, bf2f(v7[j]), acc[j]);
    } else {
        s16x4 v0 = *(const s16x4*)p0;
        s16x4 v1 = *(const s16x4*)p1;
        s16x4 v2 = *(const s16x4*)p2;
        s16x4 v3 = *(const s16x4*)p3;
        s16x4 v4 = *(const s16x4*)p4;
        s16x4 v5 = *(const s16x4*)p5;
        s16x4 v6 = *(const s16x4*)p6;
        s16x4 v7 = *(const s16x4*)p7;
#pragma unroll
        for (int j = 0; j < 4; ++j) acc[j] = fmaf(c0, bf2f(v0[j]), acc[j]);
#pragma unroll
        for (int j = 0; j < 4; ++j) acc[j] = fmaf(c1, bf2f(v1[j]), acc[j]);
#pragma unroll
        for (int j = 0; j < 4; ++j) acc[j] = fmaf(c2, bf2f(v2[j]), acc[j]);
#pragma unroll
        for (int j = 0; j < 4; ++j) acc[j] = fmaf(c3, bf2f(v3[j]), acc[j]);
#pragma unroll
        for (int j = 0; j < 4; ++j) acc[j] = fmaf(c4, bf2f(v4[j]), acc[j]);
#pragma unroll
        for (int j = 0; j < 4; ++j) acc[j] = fmaf(c5, bf2f(v5[j]), acc[j]);
#pragma unroll
        for (int j = 0; j < 4; ++j) acc[j] = fmaf(c6, bf2f(v6[j]), acc[j]);
#pragma unroll
        for (int j = 0; j < 4; ++j) acc[j] = fmaf(c7, bf2f(v7[j]), acc[j]);
    }
}

// ---- fused aggregate + GEMM -------------------------------------------------
// Per block: 16 nodes. Phase 1: 16 lanes/node gather-aggregate, 8 gathers in
// flight, int4 index loads (scalar head to 16B-align; fma order ascending e).
// Phase 2: 4 waves, wave w computes cols w*16..+15 of tile @ Wt^T.
template <int FW, bool OUT_F32>
__global__ __launch_bounds__(256) void agg_mm(
    const short* __restrict__ h, const int* __restrict__ rowptr,
    const int* __restrict__ csr_src, const float* __restrict__ dinv,
    const float* __restrict__ bias_pre, const short* __restrict__ Wt,
    const float* __restrict__ bias_post, void* __restrict__ Yv, int n,
    int ncreal) {
    constexpr int FPL = FW / 16;   // bf16 feats per lane (8 or 4)
    constexpr int LDW = FW + 8;    // padded row
    constexpr int KS = FW / 32;
    __shared__ short tile[16][LDW];
    const int tid = threadIdx.x;
    const int grp = tid >> 4;
    const int l16 = tid & 15;
    const int node = blockIdx.x * 16 + grp;

    float acc[FPL];
#pragma unroll
    for (int j = 0; j < FPL; ++j) acc[j] = 0.f;

    if (node < n) {
        const float di = dinv[node];
#pragma unroll
        for (int j = 0; j < FPL; ++j) acc[j] = bias_pre[l16 * FPL + j];
        gather1<FW>(h, dinv, di, node, l16, acc);  // self-loop (dinv[node]*di = di^2)
        int e = rowptr[node];
        const int end = rowptr[node + 1];
        while (e < end && (e & 3)) {  // align to int4
            gather1<FW>(h, dinv, di, csr_src[e], l16, acc);
            ++e;
        }
        for (; e + 7 < end; e += 8) {
            int4 sa = *(const int4*)&csr_src[e];
            int4 sb = *(const int4*)&csr_src[e + 4];
            gather8<FW>(h, dinv, di, sa, sb, l16, acc);
        }
        for (; e + 3 < end; e += 4) {
            int4 sa = *(const int4*)&csr_src[e];
            gather4<FW>(h, dinv, di, sa, l16, acc);
        }
        for (; e < end; ++e)
            gather1<FW>(h, dinv, di, csr_src[e], l16, acc);
    }
    // relu -> bf16 -> LDS tile (OOB rows get zeros: acc stayed 0)
    if constexpr (FPL == 8) {
        short8 o;
#pragma unroll
        for (int j = 0; j < 8; ++j) o[j] = f2bf(fmaxf(acc[j], 0.f));
        *(short8*)&tile[grp][l16 * 8] = o;
    } else {
        s16x4 o;
#pragma unroll
        for (int j = 0; j < 4; ++j) o[j] = f2bf(fmaxf(acc[j], 0.f));
        *(s16x4*)&tile[grp][l16 * 4] = o;
    }
    __syncthreads();

    // MFMA: tile[16][FW] @ Wt^T -> [16][64]
    const int wave = tid >> 6;
    const int lane = tid & 63;
    const int l15 = lane & 15;
    const int kg = lane >> 4;
    const int col = wave * 16 + l15;
    short8 af[KS];
#pragma unroll
    for (int ks = 0; ks < KS; ++ks)
        af[ks] = *(const short8*)&tile[l15][kg * 8 + ks * 32];
    f32x4 c2 = {0.f, 0.f, 0.f, 0.f};
    const short* wr = Wt + (long)col * FW + kg * 8;
#pragma unroll
    for (int ks = 0; ks < KS; ++ks) {
        short8 bfr = *(const short8*)(wr + ks * 32);
        c2 = __builtin_amdgcn_mfma_f32_16x16x32_bf16(af[ks], bfr, c2, 0, 0, 0);
    }
    const int rb = blockIdx.x * 16 + kg * 4;
    if (OUT_F32) {
        float* Y = (float*)Yv;
#pragma unroll
        for (int j = 0; j < 4; ++j) {
            int g = rb + j;
            if (g < n && col < ncreal)
                Y[(long)g * ncreal + col] = c2[j] + bias_post[col];
        }
    } else {
        short* Y = (short*)Yv;
#pragma unroll
        for (int j = 0; j < 4; ++j) {
            int g = rb + j;
            if (g < n) Y[(long)g * 64 + col] = f2bf(c2[j]);
        }
    }
}

// ---- launch -----------------------------------------------------------------
static inline size_t al256(size_t x) { return (x + 255) & ~(size_t)255; }

extern "C" void kernel_launch(void* const* d_in, const int* in_sizes, int n_in,
                              void* d_out, int out_size, void* d_ws, size_t ws_size,
                              hipStream_t stream) {
    const float* x    = (const float*)d_in[0];
    const int*   eraw = (const int*)d_in[1];
    const float* W1   = (const float*)d_in[2];
    const float* b1   = (const float*)d_in[3];
    const float* W2   = (const float*)d_in[4];
    const float* b2   = (const float*)d_in[5];
    const float* Wh   = (const float*)d_in[6];
    const float* bh   = (const float*)d_in[7];
    float* out = (float*)d_out;
    const int n = in_sizes[0] / F_IN;
    const int E = in_sizes[1] / 2;
    const int nbuck = (n + 255) >> 8;  // 196 for n=50k

    // ---- workspace layout ----
    char* p = (char*)d_ws;
    unsigned* done  = (unsigned*)p; p += 256;     // modulo-trick counter (no init needed)
    float* dinv     = (float*)p; p += al256((size_t)n * 4);
    int*   rowptr   = (int*)p;   p += al256((size_t)(n + 1) * 4);
    int*   parthist = (int*)p;   p += al256((size_t)EB * nbuck * 4);
    int*   totals   = (int*)p;   p += al256((size_t)NBUCK_MAX * 4);
    int*   bbase    = (int*)p;   p += al256((size_t)(nbuck + 1) * 4);
    int*   csr_src  = (int*)p;   p += al256((size_t)E * 4);
    short* W1t      = (short*)p; p += al256((size_t)HH1 * F_IN * 2);
    short* W2t      = (short*)p; p += al256((size_t)HH2 * HH1 * 2);
    short* Whtp     = (short*)p; p += al256((size_t)64 * HH2 * 2);
    int2*  tmp      = (int2*)p;  p += al256((size_t)E * 8);         // 5 MB
    short* h1       = (short*)p; p += al256((size_t)n * HH1 * 2);   // 12.8 MB
    short* h2       = (short*)p;                                    // 6.4 MB

    dim3 blk(256);
    // CSR build: histogram -> parallel column scan -> scatter (overlapped w/ GEMM1)
    bucket_count<<<EB, blk, 0, stream>>>(eraw, E, nbuck, parthist,
                                         W1, W2, Wh, W1t, W2t, Whtp);
    scan_cols<<<NBUCK_MAX, blk, 0, stream>>>(parthist, totals, bbase, done, nbuck, E);
    scatter_gemm1<<<EB + (n + 63) / 64, blk, 0, stream>>>(
        eraw, E, nbuck, parthist, bbase, tmp, x, W1t, h1, n);
    bucket_finalize<<<nbuck, blk, 0, stream>>>(tmp, bbase, rowptr, dinv, csr_src, n, nbuck);

    // fused: agg(h1)+b1+relu -> @W2 -> h2
    agg_mm<HH1, false><<<(n + 15) / 16, blk, 0, stream>>>(
        h1, rowptr, csr_src, dinv, b1, W2t, nullptr, h2, n, HH2);
    // fused: agg(h2)+b2+relu -> @Wh + bh -> out (fp32, 50 cols)
    agg_mm<HH2, true><<<(n + 15) / 16, blk, 0, stream>>>(
        h2, rowptr, csr_src, dinv, b2, Whtp, bh, out, n, FOUT);
}

// Round 14
// 122.931 us; speedup vs baseline: 1.1362x; 1.1035x over previous
//
#include <hip/hip_runtime.h>

#define F_IN 128
#define HH1 128
#define HH2 64
#define FOUT 50
#define EB 256          // edge-pass blocks (A1/A3)
#define NBUCK_MAX 256   // max coarse buckets (n <= 64k)

typedef __attribute__((ext_vector_type(8))) short short8;
typedef __attribute__((ext_vector_type(4))) short s16x4;
typedef __attribute__((ext_vector_type(4))) float f32x4;

__device__ inline short f2bf(float f) {  // RNE fp32->bf16
    union { float f; unsigned u; } v; v.f = f;
    unsigned r = v.u + 0x7fffu + ((v.u >> 16) & 1u);
    return (short)(r >> 16);
}
__device__ inline float bf2f(short s) {
    union { float f; unsigned u; } v; v.u = ((unsigned)(unsigned short)s) << 16;
    return v.f;
}

// Per-block int64-vs-int32 self-detection: int64 node ids < 2^31 have all-zero
// high (odd) words in the first 512 int32 words. Returns 1 if int64.
__device__ inline int detect64(const unsigned* raw) {
    __shared__ int s_is64;
    if (threadIdx.x == 0) s_is64 = 1;
    __syncthreads();
    if (raw[2 * threadIdx.x + 1] != 0u) atomicAnd(&s_is64, 0);
    __syncthreads();
    return s_is64;
}

// ---- A1: coarse histogram (dst>>8), per-wave sub-hists, + weight transpose --
__global__ __launch_bounds__(256) void bucket_count(
    const int* __restrict__ raw, int E, int nbuck, int* __restrict__ parthist,
    const float* __restrict__ W1, const float* __restrict__ W2,
    const float* __restrict__ Wh, short* __restrict__ W1t,
    short* __restrict__ W2t, short* __restrict__ Wht) {
    __shared__ int hist[4][NBUCK_MAX];   // one sub-hist per wave
    const int tid = threadIdx.x;
    const int wv = tid >> 6;
    int is64 = detect64((const unsigned*)raw);
    for (int k = tid; k < 4 * NBUCK_MAX; k += 256) ((int*)hist)[k] = 0;
    __syncthreads();
    const int CH = (E + EB - 1) / EB;
    const int e0 = blockIdx.x * CH, e1 = min(E, e0 + CH);
    for (int e = e0 + tid; e < e1; e += 256) {
        int d = is64 ? raw[2 * (long)E + 2 * e] : raw[E + e];
        atomicAdd(&hist[wv][d >> 8], 1);
    }
    __syncthreads();
    for (int k = tid; k < nbuck; k += 256)
        parthist[blockIdx.x * nbuck + k] =
            hist[0][k] + hist[1][k] + hist[2][k] + hist[3][k];
    // fused weight transpose (independent work)
    const int T1 = HH1 * F_IN, T2 = HH2 * HH1, T3 = 64 * HH2;
    int idx = blockIdx.x * 256 + tid;
    if (idx < T1) {
        int c = idx / F_IN, k = idx - c * F_IN;
        W1t[idx] = f2bf(W1[(long)k * HH1 + c]);
    } else if (idx < T1 + T2) {
        int i = idx - T1;
        int c = i / HH1, k = i - c * HH1;
        W2t[i] = f2bf(W2[(long)k * HH2 + c]);
    } else if (idx < T1 + T2 + T3) {
        int i = idx - T1 - T2;
        int c = i / HH2, k = i - c * HH2;
        Wht[i] = f2bf((c < FOUT) ? Wh[(long)k * FOUT + c] : 0.f);
    }
}

// ---- A2: PARALLEL column scan + (last block) bucket-base scan ---------------
__global__ __launch_bounds__(256) void scan_cols(
    int* __restrict__ parthist, int* __restrict__ totals, int* __restrict__ bbase,
    unsigned* __restrict__ done, int nbuck, int E) {
    const int k = blockIdx.x;   // 0..255
    const int t = threadIdx.x;
    __shared__ int sh[256];
    int v = 0;
    if (k < nbuck) v = parthist[t * nbuck + k];
    sh[t] = v;
    __syncthreads();
    for (int off = 1; off < 256; off <<= 1) {
        int tv = (t >= off) ? sh[t - off] : 0;
        __syncthreads();
        sh[t] += tv;
        __syncthreads();
    }
    if (k < nbuck) parthist[t * nbuck + k] = sh[t] - v;  // exclusive col-prefix
    if (t == 255) totals[k] = (k < nbuck) ? sh[255] : 0;
    __threadfence();
    __syncthreads();
    __shared__ unsigned s_old;
    if (t == 0) s_old = atomicAdd(done, 1u);
    __syncthreads();
    if (s_old % 256u != 255u) return;
    __threadfence();  // acquire: see all blocks' totals/parthist writes
    int tv2 = totals[t];
    sh[t] = tv2;
    __syncthreads();
    for (int off = 1; off < 256; off <<= 1) {
        int tt = (t >= off) ? sh[t - off] : 0;
        __syncthreads();
        sh[t] += tt;
        __syncthreads();
    }
    if (t < nbuck) bbase[t] = sh[t] - tv2;  // exclusive
    if (t == 0) bbase[nbuck] = E;
}

// ---- A3 + layer-1 GEMM merged in one dispatch -------------------------------
__global__ __launch_bounds__(256) void scatter_gemm1(
    const int* __restrict__ raw, int E, int nbuck,
    const int* __restrict__ parthist, const int* __restrict__ bbase,
    int2* __restrict__ tmp,
    const float* __restrict__ x, const short* __restrict__ W1t,
    short* __restrict__ h1, int n) {
    const int tid = threadIdx.x;
    if (blockIdx.x < EB) {
        __shared__ int cur[NBUCK_MAX];
        int is64 = detect64((const unsigned*)raw);
        for (int k = tid; k < nbuck; k += 256)
            cur[k] = bbase[k] + parthist[blockIdx.x * nbuck + k];
        __syncthreads();
        const int CH = (E + EB - 1) / EB;
        const int e0 = blockIdx.x * CH, e1 = min(E, e0 + CH);
        for (int e = e0 + tid; e < e1; e += 256) {
            int s, d;
            if (is64) {
                s = raw[2 * e];
                d = raw[2 * (long)E + 2 * e];
            } else {
                s = raw[e];
                d = raw[E + e];
            }
            int pos = atomicAdd(&cur[d >> 8], 1);
            tmp[pos] = make_int2(s, d);
        }
        return;
    }
    // ---- GEMM1 part ----
    const int bid = blockIdx.x - EB;
    const int wave = tid >> 6;
    const int lane = tid & 63;
    const int l15 = lane & 15;
    const int kg = lane >> 4;
    const int rowbase = bid * 64 + wave * 16;
    const int arow = rowbase + l15;
    constexpr int KS = F_IN / 32;

    short8 af[KS];
    if (arow < n) {
        const float* xr = x + (long)arow * F_IN + kg * 8;
#pragma unroll
        for (int ks = 0; ks < KS; ++ks) {
            float4 f0 = *(const float4*)(xr + ks * 32);
            float4 f1 = *(const float4*)(xr + ks * 32 + 4);
            short8 a;
            a[0] = f2bf(f0.x); a[1] = f2bf(f0.y); a[2] = f2bf(f0.z); a[3] = f2bf(f0.w);
            a[4] = f2bf(f1.x); a[5] = f2bf(f1.y); a[6] = f2bf(f1.z); a[7] = f2bf(f1.w);
            af[ks] = a;
        }
    } else {
#pragma unroll
        for (int ks = 0; ks < KS; ++ks) af[ks] = (short8)0;
    }
    const int crowb = rowbase + kg * 4;
#pragma unroll
    for (int ct = 0; ct < HH1 / 16; ++ct) {
        const int col = ct * 16 + l15;
        const short* wr = W1t + (long)col * F_IN + kg * 8;
        f32x4 acc = {0.f, 0.f, 0.f, 0.f};
#pragma unroll
        for (int ks = 0; ks < KS; ++ks) {
            short8 bfr = *(const short8*)(wr + ks * 32);
            acc = __builtin_amdgcn_mfma_f32_16x16x32_bf16(af[ks], bfr, acc, 0, 0, 0);
        }
#pragma unroll
        for (int j = 0; j < 4; ++j) {
            int r = crowb + j;
            if (r < n) h1[(long)r * HH1 + col] = f2bf(acc[j]);
        }
    }
}

// ---- B: per-bucket fine sort -> rowptr, dinv, csr_src -----------------------
__global__ __launch_bounds__(256) void bucket_finalize(
    const int2* __restrict__ tmp, const int* __restrict__ bbase,
    int* __restrict__ rowptr, float* __restrict__ dinv,
    int* __restrict__ csr_src, int n, int nbuck) {
    __shared__ int deg[256];
    __shared__ int cur[256];
    __shared__ int sh[256];
    const int k = blockIdx.x;
    const int tid = threadIdx.x;
    const int b0 = bbase[k], b1 = bbase[k + 1];
    deg[tid] = 0;
    __syncthreads();
    for (int e = b0 + tid; e < b1; e += 256) atomicAdd(&deg[tmp[e].y & 255], 1);
    __syncthreads();
    int v = deg[tid];
    sh[tid] = v;
    __syncthreads();
    for (int off = 1; off < 256; off <<= 1) {
        int t = (tid >= off) ? sh[tid - off] : 0;
        __syncthreads();
        sh[tid] += t;
        __syncthreads();
    }
    int excl = sh[tid] - v;
    cur[tid] = excl;
    int node = (k << 8) + tid;
    if (node < n) {
        rowptr[node] = b0 + excl;
        dinv[node] = rsqrtf((float)v + 1.0f);  // +1 self-loop
    }
    if (k == 0 && tid == 0) rowptr[n] = bbase[nbuck];
    __syncthreads();
    for (int e = b0 + tid; e < b1; e += 256) {
        int2 sd = tmp[e];
        int p = atomicAdd(&cur[sd.y & 255], 1);
        csr_src[b0 + p] = sd.x;
    }
}

// ---- gather helper (proven ILP-4 coef form) ---------------------------------
template <int FPL>
__device__ inline void gather1(const short* p0, float c0, float* acc) {
    if constexpr (FPL == 8) {
        short8 v0 = *(const short8*)p0;
#pragma unroll
        for (int j = 0; j < 8; ++j) acc[j] = fmaf(c0, bf2f(v0[j]), acc[j]);
    } else {
        s16x4 v0 = *(const s16x4*)p0;
#pragma unroll
        for (int j = 0; j < 4; ++j) acc[j] = fmaf(c0, bf2f(v0[j]), acc[j]);
    }
}

// ---- fused aggregate + GEMM (r11-proven ILP-4 form) -------------------------
// Per block: 16 nodes. Phase 1: 16 lanes/node gather-aggregate (4-wide ILP)
//   t[i] = relu(bias_pre + dinv[i]^2*h[i] + sum_e dinv[s]*dinv[i]*h[s]) (bf16)
// into LDS tile [16][FW+8]. Phase 2: 4 waves, wave w computes cols w*16..+15
// of tile @ Wt^T (Wt is [64][FW]), writes bf16 Y[n][64] or fp32 out + bias_post.
template <int FW, bool OUT_F32>
__global__ __launch_bounds__(256) void agg_mm(
    const short* __restrict__ h, const int* __restrict__ rowptr,
    const int* __restrict__ csr_src, const float* __restrict__ dinv,
    const float* __restrict__ bias_pre, const short* __restrict__ Wt,
    const float* __restrict__ bias_post, void* __restrict__ Yv, int n,
    int ncreal) {
    constexpr int FPL = FW / 16;   // bf16 feats per lane (8 or 4)
    constexpr int LDW = FW + 8;    // padded row
    constexpr int KS = FW / 32;
    __shared__ short tile[16][LDW];
    const int tid = threadIdx.x;
    const int grp = tid >> 4;
    const int l16 = tid & 15;
    const int node = blockIdx.x * 16 + grp;

    float acc[FPL];
#pragma unroll
    for (int j = 0; j < FPL; ++j) acc[j] = 0.f;

    if (node < n) {
        const float di = dinv[node];
#pragma unroll
        for (int j = 0; j < FPL; ++j) acc[j] = bias_pre[l16 * FPL + j];
        gather1<FPL>(h + (long)node * FW + l16 * FPL, di * di, acc);  // self-loop
        int e = rowptr[node];
        const int end = rowptr[node + 1];
        for (; e + 3 < end; e += 4) {  // 4 independent gathers in flight
            int s0 = csr_src[e];
            int s1 = csr_src[e + 1];
            int s2 = csr_src[e + 2];
            int s3 = csr_src[e + 3];
            const short* p0 = h + (long)s0 * FW + l16 * FPL;
            const short* p1 = h + (long)s1 * FW + l16 * FPL;
            const short* p2 = h + (long)s2 * FW + l16 * FPL;
            const short* p3 = h + (long)s3 * FW + l16 * FPL;
            float c0 = dinv[s0] * di;
            float c1 = dinv[s1] * di;
            float c2 = dinv[s2] * di;
            float c3 = dinv[s3] * di;
            if constexpr (FPL == 8) {
                short8 v0 = *(const short8*)p0;
                short8 v1 = *(const short8*)p1;
                short8 v2 = *(const short8*)p2;
                short8 v3 = *(const short8*)p3;
#pragma unroll
                for (int j = 0; j < 8; ++j) acc[j] = fmaf(c0, bf2f(v0[j]), acc[j]);
#pragma unroll
                for (int j = 0; j < 8; ++j) acc[j] = fmaf(c1, bf2f(v1[j]), acc[j]);
#pragma unroll
                for (int j = 0; j < 8; ++j) acc[j] = fmaf(c2, bf2f(v2[j]), acc[j]);
#pragma unroll
                for (int j = 0; j < 8; ++j) acc[j] = fmaf(c3, bf2f(v3[j]), acc[j]);
            } else {
                s16x4 v0 = *(const s16x4*)p0;
                s16x4 v1 = *(const s16x4*)p1;
                s16x4 v2 = *(const s16x4*)p2;
                s16x4 v3 = *(const s16x4*)p3;
#pragma unroll
                for (int j = 0; j < 4; ++j) acc[j] = fmaf(c0, bf2f(v0[j]), acc[j]);
#pragma unroll
                for (int j = 0; j < 4; ++j) acc[j] = fmaf(c1, bf2f(v1[j]), acc[j]);
#pragma unroll
                for (int j = 0; j < 4; ++j) acc[j] = fmaf(c2, bf2f(v2[j]), acc[j]);
#pragma unroll
                for (int j = 0; j < 4; ++j) acc[j] = fmaf(c3, bf2f(v3[j]), acc[j]);
            }
        }
        for (; e < end; ++e) {
            int s0 = csr_src[e];
            gather1<FPL>(h + (long)s0 * FW + l16 * FPL, dinv[s0] * di, acc);
        }
    }
    // relu -> bf16 -> LDS tile (OOB rows get zeros: acc stayed 0)
    if constexpr (FPL == 8) {
        short8 o;
#pragma unroll
        for (int j = 0; j < 8; ++j) o[j] = f2bf(fmaxf(acc[j], 0.f));
        *(short8*)&tile[grp][l16 * 8] = o;
    } else {
        s16x4 o;
#pragma unroll
        for (int j = 0; j < 4; ++j) o[j] = f2bf(fmaxf(acc[j], 0.f));
        *(s16x4*)&tile[grp][l16 * 4] = o;
    }
    __syncthreads();

    // MFMA: tile[16][FW] @ Wt^T -> [16][64]
    const int wave = tid >> 6;
    const int lane = tid & 63;
    const int l15 = lane & 15;
    const int kg = lane >> 4;
    const int col = wave * 16 + l15;
    short8 af[KS];
#pragma unroll
    for (int ks = 0; ks < KS; ++ks)
        af[ks] = *(const short8*)&tile[l15][kg * 8 + ks * 32];
    f32x4 c2 = {0.f, 0.f, 0.f, 0.f};
    const short* wr = Wt + (long)col * FW + kg * 8;
#pragma unroll
    for (int ks = 0; ks < KS; ++ks) {
        short8 bfr = *(const short8*)(wr + ks * 32);
        c2 = __builtin_amdgcn_mfma_f32_16x16x32_bf16(af[ks], bfr, c2, 0, 0, 0);
    }
    const int rb = blockIdx.x * 16 + kg * 4;
    if (OUT_F32) {
        float* Y = (float*)Yv;
#pragma unroll
        for (int j = 0; j < 4; ++j) {
            int g = rb + j;
            if (g < n && col < ncreal)
                Y[(long)g * ncreal + col] = c2[j] + bias_post[col];
        }
    } else {
        short* Y = (short*)Yv;
#pragma unroll
        for (int j = 0; j < 4; ++j) {
            int g = rb + j;
            if (g < n) Y[(long)g * 64 + col] = f2bf(c2[j]);
        }
    }
}

// ---- launch -----------------------------------------------------------------
static inline size_t al256(size_t x) { return (x + 255) & ~(size_t)255; }

extern "C" void kernel_launch(void* const* d_in, const int* in_sizes, int n_in,
                              void* d_out, int out_size, void* d_ws, size_t ws_size,
                              hipStream_t stream) {
    const float* x    = (const float*)d_in[0];
    const int*   eraw = (const int*)d_in[1];
    const float* W1   = (const float*)d_in[2];
    const float* b1   = (const float*)d_in[3];
    const float* W2   = (const float*)d_in[4];
    const float* b2   = (const float*)d_in[5];
    const float* Wh   = (const float*)d_in[6];
    const float* bh   = (const float*)d_in[7];
    float* out = (float*)d_out;
    const int n = in_sizes[0] / F_IN;
    const int E = in_sizes[1] / 2;
    const int nbuck = (n + 255) >> 8;  // 196 for n=50k

    // ---- workspace layout ----
    char* p = (char*)d_ws;
    unsigned* done  = (unsigned*)p; p += 256;     // modulo-trick counter (no init needed)
    float* dinv     = (float*)p; p += al256((size_t)n * 4);
    int*   rowptr   = (int*)p;   p += al256((size_t)(n + 1) * 4);
    int*   parthist = (int*)p;   p += al256((size_t)EB * nbuck * 4);
    int*   totals   = (int*)p;   p += al256((size_t)NBUCK_MAX * 4);
    int*   bbase    = (int*)p;   p += al256((size_t)(nbuck + 1) * 4);
    int*   csr_src  = (int*)p;   p += al256((size_t)E * 4);
    short* W1t      = (short*)p; p += al256((size_t)HH1 * F_IN * 2);
    short* W2t      = (short*)p; p += al256((size_t)HH2 * HH1 * 2);
    short* Whtp     = (short*)p; p += al256((size_t)64 * HH2 * 2);
    int2*  tmp      = (int2*)p;  p += al256((size_t)E * 8);         // 5 MB
    short* h1       = (short*)p; p += al256((size_t)n * HH1 * 2);   // 12.8 MB
    short* h2       = (short*)p;                                    // 6.4 MB

    dim3 blk(256);
    // CSR build: histogram -> parallel column scan -> scatter (overlapped w/ GEMM1)
    bucket_count<<<EB, blk, 0, stream>>>(eraw, E, nbuck, parthist,
                                         W1, W2, Wh, W1t, W2t, Whtp);
    scan_cols<<<NBUCK_MAX, blk, 0, stream>>>(parthist, totals, bbase, done, nbuck, E);
    scatter_gemm1<<<EB + (n + 63) / 64, blk, 0, stream>>>(
        eraw, E, nbuck, parthist, bbase, tmp, x, W1t, h1, n);
    bucket_finalize<<<nbuck, blk, 0, stream>>>(tmp, bbase, rowptr, dinv, csr_src, n, nbuck);

    // fused: agg(h1)+b1+relu -> @W2 -> h2
    agg_mm<HH1, false><<<(n + 15) / 16, blk, 0, stream>>>(
        h1, rowptr, csr_src, dinv, b1, W2t, nullptr, h2, n, HH2);
    // fused: agg(h2)+b2+relu -> @Wh + bh -> out (fp32, 50 cols)
    agg_mm<HH2, true><<<(n + 15) / 16, blk, 0, stream>>>(
        h2, rowptr, csr_src, dinv, b2, Whtp, bh, out, n, FOUT);
}